// Round 1
// baseline (220.529 us; speedup 1.0000x reference)
//
#include <hip/hip_runtime.h>
#include <math.h>

#define NFEAT 20

__global__ __launch_bounds__(256) void deepdft_expansion_kernel(
    const float* __restrict__ src,
    const float* __restrict__ tgt,
    float* __restrict__ out,
    unsigned int N, unsigned int M)
{
    const float CUT  = 4.0f;
    const float EPS  = 1e-11f;
    const float BOHR = 0.5291772105638411f;
    const float PI_F = 3.14159265358979323846f;

    const unsigned int total = N * M;

    float* __restrict__ dist_o = out;
    float* __restrict__ dir_o  = out + (size_t)total;          // [total][3]
    float* __restrict__ mask_o = out + (size_t)4 * total;      // [total]
    float* __restrict__ exp_o  = out + (size_t)5 * total;      // [total][20]

    const unsigned int stride = gridDim.x * blockDim.x;
    for (unsigned int idx = blockIdx.x * blockDim.x + threadIdx.x;
         idx < total; idx += stride) {
        unsigned int n = idx / M;
        unsigned int m = idx - n * M;

        // source broadcast within wave (n uniform over 64 lanes when M%64==0),
        // target coalesced
        float sx = src[3u*n + 0], sy = src[3u*n + 1], sz = src[3u*n + 2];
        float tx = tgt[3u*m + 0], ty = tgt[3u*m + 1], tz = tgt[3u*m + 2];

        float dx = tx - sx, dy = ty - sy, dz = tz - sz;
        float d2 = fmaf(dx, dx, fmaf(dy, dy, dz * dz));
        float dist = sqrtf(d2);
        float inv = 1.0f / (dist + EPS);

        dist_o[idx] = dist;
        mask_o[idx] = (dist < CUT) ? 1.0f : 0.0f;

        size_t di = (size_t)3 * idx;
        dir_o[di + 0] = dx * inv;
        dir_o[di + 1] = dy * inv;
        dir_o[di + 2] = dz * inv;

        // sinc radial basis: sin(n*pi*d/CUT)/d, n = 1..20, d in Bohr
        float d    = fmaf(dist, BOHR, EPS);
        float invd = 1.0f / d;
        float x    = (PI_F / CUT) * d;

        float s = __sinf(x);
        float c = __cosf(x);
        float twoC = 2.0f * c;

        // Chebyshev recurrence: sin(k*x) = 2cos(x)*sin((k-1)x) - sin((k-2)x)
        float sv[NFEAT];
        float sp = 0.0f;   // sin(0)
        float sc = s;      // sin(x)
        #pragma unroll
        for (int f = 0; f < NFEAT; ++f) {
            sv[f] = sc * invd;
            float nx = fmaf(twoC, sc, -sp);
            sp = sc;
            sc = nx;
        }

        // 80 B contiguous per thread; segment base is 16B-aligned and 20*4B=80B
        // per row keeps float4 alignment.
        float4* e4 = reinterpret_cast<float4*>(exp_o + (size_t)idx * NFEAT);
        #pragma unroll
        for (int q = 0; q < NFEAT / 4; ++q) {
            e4[q] = make_float4(sv[4*q+0], sv[4*q+1], sv[4*q+2], sv[4*q+3]);
        }
    }
}

extern "C" void kernel_launch(void* const* d_in, const int* in_sizes, int n_in,
                              void* d_out, int out_size, void* d_ws, size_t ws_size,
                              hipStream_t stream) {
    const float* src = (const float*)d_in[0];   // [1, N, 3] float32
    const float* tgt = (const float*)d_in[1];   // [1, M, 3] float32
    float* out = (float*)d_out;

    unsigned int N = (unsigned int)(in_sizes[0] / 3);
    unsigned int M = (unsigned int)(in_sizes[1] / 3);
    unsigned int total = N * M;

    const unsigned int block = 256;
    unsigned int blocks = (total + block - 1) / block;
    // grid-stride: keep all blocks co-resident (256 CU * 8 blocks of 256 thr)
    if (blocks > 2048u) blocks = 2048u;

    deepdft_expansion_kernel<<<blocks, block, 0, stream>>>(src, tgt, out, N, M);
}

// Round 2
// 159.688 us; speedup vs baseline: 1.3810x; 1.3810x over previous
//
#include <hip/hip_runtime.h>
#include <math.h>

#define TILE 256
#define NFEAT 20

__global__ __launch_bounds__(256) void deepdft_expansion_kernel(
    const float* __restrict__ src,
    const float* __restrict__ tgt,
    float* __restrict__ out,
    unsigned int N, unsigned int M)
{
    const float CUT  = 4.0f;
    const float EPS  = 1e-11f;
    const float BOHR = 0.5291772105638411f;
    const float PI_F = 3.14159265358979323846f;

    const unsigned int total = N * M;

    float* __restrict__ dist_o = out;
    float* __restrict__ dir_o  = out + (size_t)total;          // [total][3]
    float* __restrict__ mask_o = out + (size_t)4 * total;      // [total]
    float* __restrict__ exp_o  = out + (size_t)5 * total;      // [total][20]

    // LDS staging: dir interleaved [tid][3] (write 2-way max, read linear
    // conflict-free); x and 1/d SoA (conflict-free both sides). 5 KB total.
    __shared__ float lds_dir[TILE * 3];
    __shared__ float lds_x[TILE];
    __shared__ float lds_invd[TILE];

    const unsigned int tid = threadIdx.x;
    const unsigned int tiles = (total + TILE - 1) / TILE;

    for (unsigned int tile = blockIdx.x; tile < tiles; tile += gridDim.x) {
        const unsigned int base = tile * TILE;
        const unsigned int idx  = base + tid;

        if (idx < total) {
            unsigned int n = idx / M;       // source (row) index
            unsigned int m = idx - n * M;   // target (col) index

            float sx = src[3u*n + 0], sy = src[3u*n + 1], sz = src[3u*n + 2];
            float tx = tgt[3u*m + 0], ty = tgt[3u*m + 1], tz = tgt[3u*m + 2];

            float dx = tx - sx, dy = ty - sy, dz = tz - sz;
            float d2   = fmaf(dx, dx, fmaf(dy, dy, dz * dz));
            float dist = sqrtf(d2);
            float inv  = 1.0f / (dist + EPS);

            dist_o[idx] = dist;                          // coalesced dword
            mask_o[idx] = (dist < CUT) ? 1.0f : 0.0f;    // coalesced dword

            lds_dir[3u*tid + 0] = dx * inv;
            lds_dir[3u*tid + 1] = dy * inv;
            lds_dir[3u*tid + 2] = dz * inv;

            float d = fmaf(dist, BOHR, EPS);
            lds_invd[tid] = 1.0f / d;
            lds_x[tid]    = (PI_F / CUT) * d;            // x = pi*d/CUT
        }
        __syncthreads();

        // ---- direction copy-out: linear LDS->global, fully coalesced ----
        {
            float* gdir = dir_o + (size_t)3 * base;
            #pragma unroll
            for (int k = 0; k < 3; ++k) {
                unsigned int e = tid + (unsigned)k * TILE;    // e < 768
                unsigned int p = (e * 10923u) >> 15;          // e / 3 (exact for e<10922)
                if (base + p < total) gdir[e] = lds_dir[e];
            }
        }

        // ---- expansion: regenerate sines in output order, float4 stores ----
        {
            float4* gexp = reinterpret_cast<float4*>(exp_o + (size_t)NFEAT * base);
            #pragma unroll
            for (int k = 0; k < 5; ++k) {
                unsigned int j = tid + (unsigned)k * TILE;    // float4 idx, j < 1280
                unsigned int p = (j * 6554u) >> 15;           // j / 5 (exact for j<3276)
                unsigned int g = j - 5u * p;                  // feature group 0..4
                if (base + p < total) {
                    float x    = lds_x[p];
                    float invd = lds_invd[p];
                    float n0   = (float)(4u * g + 1u);        // first n of this group
                    float4 v;
                    v.x = __sinf( n0          * x) * invd;
                    v.y = __sinf((n0 + 1.0f)  * x) * invd;
                    v.z = __sinf((n0 + 2.0f)  * x) * invd;
                    v.w = __sinf((n0 + 3.0f)  * x) * invd;
                    gexp[j] = v;                              // coalesced 1 KiB/wave
                }
            }
        }
        __syncthreads();   // LDS reused next iteration
    }
}

extern "C" void kernel_launch(void* const* d_in, const int* in_sizes, int n_in,
                              void* d_out, int out_size, void* d_ws, size_t ws_size,
                              hipStream_t stream) {
    const float* src = (const float*)d_in[0];   // [1, N, 3] float32
    const float* tgt = (const float*)d_in[1];   // [1, M, 3] float32
    float* out = (float*)d_out;

    unsigned int N = (unsigned int)(in_sizes[0] / 3);
    unsigned int M = (unsigned int)(in_sizes[1] / 3);
    unsigned int total = N * M;

    const unsigned int block = TILE;
    unsigned int tiles = (total + TILE - 1) / TILE;
    unsigned int blocks = tiles > 2048u ? 2048u : tiles;

    deepdft_expansion_kernel<<<blocks, block, 0, stream>>>(src, tgt, out, N, M);
}

// Round 3
// 158.707 us; speedup vs baseline: 1.3895x; 1.0062x over previous
//
#include <hip/hip_runtime.h>
#include <math.h>

#define NFEAT 20

__device__ __forceinline__ float bperm(unsigned int lane, float v) {
    return __int_as_float(
        __builtin_amdgcn_ds_bpermute((int)(lane << 2), __float_as_int(v)));
}

__global__ __launch_bounds__(256) void deepdft_expansion_kernel(
    const float* __restrict__ src,
    const float* __restrict__ tgt,
    float* __restrict__ out,
    unsigned int N, unsigned int M)
{
    const float CUT  = 4.0f;
    const float EPS  = 1e-11f;
    const float BOHR = 0.5291772105638411f;
    const float PI_F = 3.14159265358979323846f;

    const unsigned int total = N * M;

    float* __restrict__ dist_o = out;
    float* __restrict__ dir_o  = out + (size_t)total;          // [total][3]
    float* __restrict__ mask_o = out + (size_t)4 * total;      // [total]
    float* __restrict__ exp_o  = out + (size_t)5 * total;      // [total][20]

    const unsigned int lane = threadIdx.x & 63u;
    const unsigned int wavesPerGrid = (gridDim.x * blockDim.x) >> 6;
    const unsigned int wtiles = (total + 63u) >> 6;

    for (unsigned int w = (blockIdx.x * blockDim.x + threadIdx.x) >> 6;
         w < wtiles; w += wavesPerGrid) {
        const unsigned int base = w << 6;          // first pair of this wave-tile
        const unsigned int idx  = base + lane;
        // keep all 64 lanes active (bpermute sources must be valid): clamp
        const unsigned int cidx = (idx < total) ? idx : (total - 1u);

        unsigned int n = cidx / M;
        unsigned int m = cidx - n * M;

        float sx = src[3u*n + 0], sy = src[3u*n + 1], sz = src[3u*n + 2];
        float tx = tgt[3u*m + 0], ty = tgt[3u*m + 1], tz = tgt[3u*m + 2];

        float dx = tx - sx, dy = ty - sy, dz = tz - sz;
        float d2   = fmaf(dx, dx, fmaf(dy, dy, dz * dz));
        float dist = sqrtf(d2);
        float inv  = 1.0f / (dist + EPS);

        if (idx < total) {
            dist_o[idx] = dist;                          // coalesced dword
            mask_o[idx] = (dist < CUT) ? 1.0f : 0.0f;    // coalesced dword
        }

        float ux = dx * inv, uy = dy * inv, uz = dz * inv;
        float d    = fmaf(dist, BOHR, EPS);
        float invd = 1.0f / d;
        float x    = (PI_F / CUT) * d;                   // x = pi*d/CUT

        // ---- direction: wave-local transpose [64][3] -> [192] linear ----
        {
            float* gdir = dir_o + (size_t)3 * base;
            #pragma unroll
            for (int k = 0; k < 3; ++k) {
                unsigned int e = lane + 64u * (unsigned)k;   // e < 192
                unsigned int p = (e * 10923u) >> 15;          // e / 3
                unsigned int c = e - 3u * p;                  // e % 3
                float vx = bperm(p, ux);
                float vy = bperm(p, uy);
                float vz = bperm(p, uz);
                float val = (c == 0u) ? vx : ((c == 1u) ? vy : vz);
                if (base + p < total) gdir[e] = val;          // coalesced dword
            }
        }

        // ---- expansion: regenerate sines in output order, float4 stores ----
        {
            float4* gexp = reinterpret_cast<float4*>(exp_o) + (size_t)5 * base;
            #pragma unroll
            for (int k = 0; k < 5; ++k) {
                unsigned int j = lane + 64u * (unsigned)k;    // float4 idx < 320
                unsigned int p = (j * 6554u) >> 15;           // j / 5
                unsigned int g = j - 5u * p;                  // j % 5
                float xv = bperm(p, x);
                float iv = bperm(p, invd);
                float n0 = (float)(4u * g + 1u);              // first n of group
                float4 v;
                v.x = __sinf( n0         * xv) * iv;
                v.y = __sinf((n0 + 1.0f) * xv) * iv;
                v.z = __sinf((n0 + 2.0f) * xv) * iv;
                v.w = __sinf((n0 + 3.0f) * xv) * iv;
                if (base + p < total) gexp[j] = v;            // coalesced 1 KiB/wave
            }
        }
    }
}

extern "C" void kernel_launch(void* const* d_in, const int* in_sizes, int n_in,
                              void* d_out, int out_size, void* d_ws, size_t ws_size,
                              hipStream_t stream) {
    const float* src = (const float*)d_in[0];   // [1, N, 3] float32
    const float* tgt = (const float*)d_in[1];   // [1, M, 3] float32
    float* out = (float*)d_out;

    unsigned int N = (unsigned int)(in_sizes[0] / 3);
    unsigned int M = (unsigned int)(in_sizes[1] / 3);
    unsigned int total = N * M;

    const unsigned int block = 256;
    unsigned int wtiles = (total + 63u) >> 6;          // one wave per 64 pairs
    unsigned int blocks = (wtiles + (block / 64) - 1) / (block / 64);
    if (blocks > 2048u) blocks = 2048u;                // grid-stride the rest

    deepdft_expansion_kernel<<<blocks, block, 0, stream>>>(src, tgt, out, N, M);
}